// Round 13
// baseline (142.675 us; speedup 1.0000x reference)
//
#include <hip/hip_runtime.h>

#define SQ 2048
#define NB 2
#define NH 16
#define DH 128
#define NKT 32                       // 64-row KV tiles
#define NQT 32                       // 64-row Q tiles
#define SCALE_L2E 0.1275174609f      // (1/sqrt(128)) * log2(e)
#define LOG2E 1.4426950408889634f
#define DEFER_THR 11.0f              // ~8 nats in log2 units

typedef _Float16 f16x8 __attribute__((ext_vector_type(8)));
typedef _Float16 f16x4 __attribute__((ext_vector_type(4)));
typedef float f32x4 __attribute__((ext_vector_type(4)));

static __device__ __forceinline__ _Float16 f2h(float f) { return (_Float16)f; }

// ---------------------------------------------------------------------------
// Pre-pass: K -> fp16 [b][t][64][128] XOR-swizzled;
//           V -> fp16 [b][t][128][64] transposed, XOR-swizzled.
// ---------------------------------------------------------------------------
__global__ __launch_bounds__(256)
void prepack(const float* __restrict__ k, const float* __restrict__ v,
             _Float16* __restrict__ kws, _Float16* __restrict__ vws) {
    const int bid   = blockIdx.x;        // 0..127
    const int which = bid >> 6;          // 0 = K, 1 = V
    const int b     = (bid >> 5) & 1;
    const int t     = bid & 31;
    const int tid   = threadIdx.x;

    if (which == 0) {
        const float* kbase = k + (size_t)t * 64 * (NB * DH) + b * DH;
        _Float16* dst = kws + ((size_t)b * NKT + t) * 8192;
        #pragma unroll
        for (int p = 0; p < 8; ++p) {
            const int id4 = p * 256 + tid;
            const int row = id4 >> 5;
            const int c0  = (id4 & 31) << 2;
            f32x4 a = *(const f32x4*)(kbase + (size_t)row * (NB * DH) + c0);
            const int e = (row * 128 + c0) ^ ((row & 7) << 3);
            f16x4 pk = { f2h(a.x), f2h(a.y), f2h(a.z), f2h(a.w) };
            *(f16x4*)(dst + e) = pk;
        }
    } else {
        const float* vbase = v + b * DH;
        _Float16* dst = vws + ((size_t)b * NKT + t) * 8192;
        const int d    = tid & 127;
        const int half = tid >> 7;
        #pragma unroll
        for (int p = 0; p < 8; ++p) {
            const int c0 = (p * 2 + half) * 4;
            float a0 = vbase[(size_t)(t * 64 + c0 + 0) * (NB * DH) + d];
            float a1 = vbase[(size_t)(t * 64 + c0 + 1) * (NB * DH) + d];
            float a2 = vbase[(size_t)(t * 64 + c0 + 2) * (NB * DH) + d];
            float a3 = vbase[(size_t)(t * 64 + c0 + 3) * (NB * DH) + d];
            const int e = (d * 64 + c0) ^ ((d & 7) << 3);
            f16x4 pk = { f2h(a0), f2h(a1), f2h(a2), f2h(a3) };
            *(f16x4*)(dst + e) = pk;
        }
    }
}

// ---------------------------------------------------------------------------
// Hot kernel: 4 waves x 16 q-rows, KVBLK=64, SINGLE-buffered K/V (40 KB LDS
// -> 4 blocks/CU, 4 waves/SIMD), T14 reg-staged async prefetch:
// issue global loads -> regs early, ds_write after barrier.
// ---------------------------------------------------------------------------
__global__ __launch_bounds__(256, 4)
void attn_fwd(const float* __restrict__ q, const _Float16* __restrict__ kws,
              const _Float16* __restrict__ vws, const float* __restrict__ sinks,
              float* __restrict__ out) {
    __shared__ _Float16 Kb[8192];        // 64x128 swizzled (16 KB)
    __shared__ _Float16 Vb[8192];        // 128x64 (V^T) swizzled (16 KB)
    __shared__ _Float16 Plds[4][1024];   // per-wave 16x64 (8 KB)

    const int tid  = threadIdx.x;
    const int w    = tid >> 6;
    const int lane = tid & 63;
    const int r    = lane & 15;
    const int g    = lane >> 4;

    const int bid  = blockIdx.x;
    const int bh   = bid & 31;
    const int b    = bh & 1;
    const int h    = bh >> 1;
    const int slot = bid >> 5;           // 0..31
    const int jj   = slot & 7;
    const int mm   = slot >> 3;
    // balanced per-CU qt set {j,15-j,16+j,31-j}: 66 tile-iters per CU
    const int qt = (mm == 0) ? jj : (mm == 1) ? 15 - jj
                 : (mm == 2) ? 16 + jj : 31 - jj;
    const int q0  = qt * 64;
    const int q0w = q0 + w * 16;
    const int sq  = q0w + r;

    // ---- Q fragments (B-operand), SCALE*log2e folded ----
    f16x8 qf[4];
    {
        const float* qrow = q + ((size_t)sq * NB + b) * (NH * DH) + h * DH;
        #pragma unroll
        for (int kc = 0; kc < 4; ++kc) {
            const int d0 = kc * 32 + g * 8;
            f32x4 a = *(const f32x4*)(qrow + d0);
            f32x4 c = *(const f32x4*)(qrow + d0 + 4);
            f16x8 t;
            t[0] = f2h(a.x * SCALE_L2E); t[1] = f2h(a.y * SCALE_L2E);
            t[2] = f2h(a.z * SCALE_L2E); t[3] = f2h(a.w * SCALE_L2E);
            t[4] = f2h(c.x * SCALE_L2E); t[5] = f2h(c.y * SCALE_L2E);
            t[6] = f2h(c.z * SCALE_L2E); t[7] = f2h(c.w * SCALE_L2E);
            qf[kc] = t;
        }
    }

    const float sink2 = sinks[h] * LOG2E;
    float m_run = sink2;                 // base-2 running max (row-uniform)
    float l_p   = 0.0f;                  // lane-local partial sum
    f32x4 acc[8];
    #pragma unroll
    for (int i = 0; i < 8; ++i) acc[i] = (f32x4)(0.0f);

    const _Float16* ktiles = kws + (size_t)b * NKT * 8192;
    const _Float16* vtiles = vws + (size_t)b * NKT * 8192;
    const int ntiles = qt + 1;
    const int wlimit = q0w + 15;         // wave live while ktb <= wlimit

    // ---- staging registers (tile in flight) ----
    f16x8 kst[4], vst[4];

    // prologue: tile 0 -> regs -> LDS; issue tile 1 -> regs
    #pragma unroll
    for (int p = 0; p < 4; ++p) {
        const int off = (p * 256 + tid) * 8;
        kst[p] = *(const f16x8*)(ktiles + off);
        vst[p] = *(const f16x8*)(vtiles + off);
    }
    asm volatile("s_waitcnt vmcnt(0)" ::: "memory");
    #pragma unroll
    for (int p = 0; p < 4; ++p) {
        const int off = (p * 256 + tid) * 8;
        *(f16x8*)(&Kb[off]) = kst[p];
        *(f16x8*)(&Vb[off]) = vst[p];
    }
    if (1 < ntiles) {
        #pragma unroll
        for (int p = 0; p < 4; ++p) {
            const int off = (p * 256 + tid) * 8;
            kst[p] = *(const f16x8*)(ktiles + 8192 + off);
            vst[p] = *(const f16x8*)(vtiles + 8192 + off);
        }
    }
    asm volatile("s_waitcnt lgkmcnt(0)" ::: "memory");
    __builtin_amdgcn_s_barrier();
    asm volatile("" ::: "memory");

    for (int it = 0; it < ntiles; ++it) {
        const int ktb = it * 64;
        if (ktb <= wlimit) {
            // ---- S^T = K * Q^T : lane holds S[q=r][kv=ktb+ct*16+g*4+i] ----
            float sv[16];
            __builtin_amdgcn_s_setprio(1);
            #pragma unroll
            for (int ct = 0; ct < 4; ++ct) {
                f32x4 sa = (f32x4)(0.0f);
                const int c = ct * 16 + r;
                #pragma unroll
                for (int kc = 0; kc < 4; ++kc) {
                    const int e = (c * 128 + kc * 32 + g * 8) ^ ((c & 7) << 3);
                    f16x8 kf = *(const f16x8*)(&Kb[e]);
                    sa = __builtin_amdgcn_mfma_f32_16x16x32_f16(kf, qf[kc], sa, 0, 0, 0);
                }
                #pragma unroll
                for (int i = 0; i < 4; ++i) sv[ct * 4 + i] = sa[i];
            }
            __builtin_amdgcn_s_setprio(0);

            // ---- causal mask (diagonal tile only) ----
            if (ktb + 63 > q0w) {
                #pragma unroll
                for (int ct = 0; ct < 4; ++ct)
                    #pragma unroll
                    for (int i = 0; i < 4; ++i) {
                        const int tk = ktb + ct * 16 + g * 4 + i;
                        if (tk > sq) sv[ct * 4 + i] = -1e30f;
                    }
            }

            // ---- softmax: zero cross-lane ops unless defer-max triggers ----
            float m0 = fmaxf(fmaxf(sv[0], sv[1]), fmaxf(sv[2], sv[3]));
            float m1 = fmaxf(fmaxf(sv[4], sv[5]), fmaxf(sv[6], sv[7]));
            float m2 = fmaxf(fmaxf(sv[8], sv[9]), fmaxf(sv[10], sv[11]));
            float m3 = fmaxf(fmaxf(sv[12], sv[13]), fmaxf(sv[14], sv[15]));
            float mx = fmaxf(fmaxf(m0, m1), fmaxf(m2, m3));

            if (!__all(mx <= m_run + DEFER_THR)) {   // defer-max (T13)
                mx = fmaxf(mx, __shfl_xor(mx, 16));
                mx = fmaxf(mx, __shfl_xor(mx, 32));
                const float mnew = fmaxf(m_run, mx);
                const float corr = __builtin_amdgcn_exp2f(m_run - mnew);
                m_run = mnew;
                l_p *= corr;
                #pragma unroll
                for (int i = 0; i < 4; ++i) {
                    const float ci = __shfl(corr, (lane & 48) | (g * 4 + i));
                    #pragma unroll
                    for (int nb = 0; nb < 8; ++nb) acc[nb][i] *= ci;
                }
            }

            #pragma unroll
            for (int i = 0; i < 16; ++i)
                sv[i] = __builtin_amdgcn_exp2f(sv[i] - m_run);
            float t0 = (sv[0] + sv[1]) + (sv[2] + sv[3]);
            float t1 = (sv[4] + sv[5]) + (sv[6] + sv[7]);
            float t2 = (sv[8] + sv[9]) + (sv[10] + sv[11]);
            float t3 = (sv[12] + sv[13]) + (sv[14] + sv[15]);
            l_p += (t0 + t1) + (t2 + t3);

            // ---- P -> per-wave LDS (C-layout -> A-layout) ----
            #pragma unroll
            for (int ct = 0; ct < 4; ++ct) {
                f16x4 pb = { f2h(sv[ct * 4 + 0]), f2h(sv[ct * 4 + 1]),
                             f2h(sv[ct * 4 + 2]), f2h(sv[ct * 4 + 3]) };
                const int c0 = ct * 16 + g * 4;
                const int e = (r * 64 + c0) ^ ((r & 7) << 3);
                *(f16x4*)(&Plds[w][e]) = pb;
            }

            // ---- O += P * V ----
            __builtin_amdgcn_s_setprio(1);
            #pragma unroll
            for (int cc = 0; cc < 2; ++cc) {
                const int ep = (r * 64 + cc * 32 + g * 8) ^ ((r & 7) << 3);
                f16x8 pf = *(const f16x8*)(&Plds[w][ep]);
                #pragma unroll
                for (int nb = 0; nb < 8; ++nb) {
                    const int d = nb * 16 + r;
                    const int ev = (d * 64 + cc * 32 + g * 8) ^ ((d & 7) << 3);
                    f16x8 vf = *(const f16x8*)(&Vb[ev]);
                    acc[nb] = __builtin_amdgcn_mfma_f32_16x16x32_f16(pf, vf, acc[nb], 0, 0, 0);
                }
            }
            __builtin_amdgcn_s_setprio(0);
        }

        // ---- T14 staging phase: regs -> LDS, issue next loads ----
        if (it + 1 < ntiles) {
            asm volatile("s_waitcnt vmcnt(0)" ::: "memory");   // tile it+1 regs landed
            __builtin_amdgcn_s_barrier();                      // all waves done reading
            asm volatile("" ::: "memory");
            #pragma unroll
            for (int p = 0; p < 4; ++p) {
                const int off = (p * 256 + tid) * 8;
                *(f16x8*)(&Kb[off]) = kst[p];
                *(f16x8*)(&Vb[off]) = vst[p];
            }
            if (it + 2 < ntiles) {   // issue tile it+2 -> regs (lands during next compute)
                const _Float16* kn = ktiles + (size_t)(it + 2) * 8192;
                const _Float16* vn = vtiles + (size_t)(it + 2) * 8192;
                #pragma unroll
                for (int p = 0; p < 4; ++p) {
                    const int off = (p * 256 + tid) * 8;
                    kst[p] = *(const f16x8*)(kn + off);
                    vst[p] = *(const f16x8*)(vn + off);
                }
            }
            asm volatile("s_waitcnt lgkmcnt(0)" ::: "memory"); // ds_writes visible
            __builtin_amdgcn_s_barrier();
            asm volatile("" ::: "memory");
        }
    }

    // ---- epilogue: merge l across lane groups once; add sink via row m ----
    float ls = l_p;
    ls += __shfl_xor(ls, 16);
    ls += __shfl_xor(ls, 32);
    #pragma unroll
    for (int i = 0; i < 4; ++i) {
        const int sel = (lane & 48) | (g * 4 + i);
        const float mi = __shfl(m_run, sel);
        const float li = __shfl(ls, sel) + __builtin_amdgcn_exp2f(sink2 - mi);
        const float rl = 1.0f / li;
        const int row = q0 + w * 16 + g * 4 + i;
        float* op = out + ((size_t)row * NB + b) * (NH * DH) + h * DH + r;
        #pragma unroll
        for (int nb = 0; nb < 8; ++nb)
            op[nb * 16] = acc[nb][i] * rl;
    }
}

extern "C" void kernel_launch(void* const* d_in, const int* in_sizes, int n_in,
                              void* d_out, int out_size, void* d_ws, size_t ws_size,
                              hipStream_t stream) {
    const float* q     = (const float*)d_in[0];
    const float* k     = (const float*)d_in[1];
    const float* v     = (const float*)d_in[2];
    const float* sinks = (const float*)d_in[3];
    float* out = (float*)d_out;

    _Float16* kws = (_Float16*)d_ws;                        // 1 MB
    _Float16* vws = kws + (size_t)NB * NKT * 8192;          // 1 MB

    prepack<<<dim3(128), 256, 0, stream>>>(k, v, kws, vws);
    attn_fwd<<<dim3(NQT * NB * NH), 256, 0, stream>>>(q, kws, vws, sinks, out);
}

// Round 14
// 131.454 us; speedup vs baseline: 1.0854x; 1.0854x over previous
//
#include <hip/hip_runtime.h>

#define SQ 2048
#define NB 2
#define NH 16
#define DH 128
#define NKT 32                       // 2048/64 KV tiles
#define NQT 16                       // 2048/128 Q tiles
#define SCALE_L2E 0.1275174609f      // (1/sqrt(128)) * log2(e)
#define LOG2E 1.4426950408889634f
#define DEFER_THR 11.0f              // ~8 nats, in log2 units

typedef _Float16 f16x8 __attribute__((ext_vector_type(8)));
typedef _Float16 f16x4 __attribute__((ext_vector_type(4)));
typedef __fp16 fp16x2 __attribute__((ext_vector_type(2)));
typedef float f32x4 __attribute__((ext_vector_type(4)));
typedef float f32x16 __attribute__((ext_vector_type(16)));
typedef unsigned int u32x4 __attribute__((ext_vector_type(4)));

static __device__ __forceinline__ _Float16 f2h(float f) { return (_Float16)f; }

static __device__ __forceinline__ unsigned int pkrtz(float a, float b) {
    fp16x2 h = __builtin_amdgcn_cvt_pkrtz(a, b);
    return __builtin_bit_cast(unsigned int, h);
}

// ---------------------------------------------------------------------------
// Pre-pass: K -> fp16 [b][kt][64][128] swizzled,
//           V -> fp16 [b][kt][128][64] transposed + swizzled.
// ---------------------------------------------------------------------------
__global__ __launch_bounds__(256)
void prepack(const float* __restrict__ k, const float* __restrict__ v,
             _Float16* __restrict__ kws, _Float16* __restrict__ vws) {
    const int tile  = blockIdx.x;        // 0..127
    const int which = tile >> 6;         // 0 = K, 1 = V
    const int b     = (tile >> 5) & 1;
    const int kt    = tile & 31;
    const int tid   = threadIdx.x;

    if (which == 0) {
        const float* kbase = k + (size_t)kt * 64 * (NB * DH) + b * DH;
        _Float16* dst = kws + ((size_t)b * NKT + kt) * 8192;
        #pragma unroll
        for (int p = 0; p < 8; ++p) {
            const int id4 = tid + p * 256;
            const int row = id4 >> 5;
            const int c0  = (id4 & 31) << 2;
            f32x4 a = *(const f32x4*)(kbase + (size_t)row * (NB * DH) + c0);
            const int e = (row * 128 + c0) ^ ((row & 7) << 3);
            f16x4 pk = { f2h(a.x), f2h(a.y), f2h(a.z), f2h(a.w) };
            *(f16x4*)(dst + e) = pk;
        }
    } else {
        const float* vbase = v + b * DH;
        _Float16* dst = vws + ((size_t)b * NKT + kt) * 8192;
        const int d    = tid & 127;
        const int half = tid >> 7;
        #pragma unroll
        for (int p = 0; p < 8; ++p) {
            const int c0 = (p * 2 + half) * 4;
            float a0 = vbase[(size_t)(kt * 64 + c0 + 0) * (NB * DH) + d];
            float a1 = vbase[(size_t)(kt * 64 + c0 + 1) * (NB * DH) + d];
            float a2 = vbase[(size_t)(kt * 64 + c0 + 2) * (NB * DH) + d];
            float a3 = vbase[(size_t)(kt * 64 + c0 + 3) * (NB * DH) + d];
            const int e = (d * 64 + c0) ^ ((d & 7) << 3);
            f16x4 pk = { f2h(a0), f2h(a1), f2h(a2), f2h(a3) };
            *(f16x4*)(dst + e) = pk;
        }
    }
}

static __device__ __forceinline__ void gload16(const _Float16* gsrc, _Float16* ldst) {
    __builtin_amdgcn_global_load_lds(
        (const __attribute__((address_space(1))) void*)gsrc,
        (__attribute__((address_space(3))) void*)ldst, 16, 0, 0);
}

// ---------------------------------------------------------------------------
// Hot kernel: 4 waves x 32 q-rows (128-row q-blocks), 32x32x16 MFMA,
// in-register P (cvt_pkrtz + permlane32_swap), O^T accumulation.
// K double-buffered, V SINGLE-buffered -> 48 KB LDS -> 3 blocks/CU,
// all 512 blocks resident from t=0. Two barriers/iter (V-visibility + K-swap).
// ---------------------------------------------------------------------------
__global__ __launch_bounds__(256, 3)
void attn_fwd(const float* __restrict__ q, const _Float16* __restrict__ kws,
              const _Float16* __restrict__ vws, const float* __restrict__ sinks,
              float* __restrict__ out) {
    __shared__ _Float16 Kb[2][8192];     // 64x128 swizzled, dbuf (32 KB)
    __shared__ _Float16 Vb[8192];        // 128x64 (V^T) swizzled, single (16 KB)

    const int tid  = threadIdx.x;
    const int w    = tid >> 6;
    const int lane = tid & 63;
    const int qc   = lane & 31;          // q column (lane-local stats)
    const int h2   = lane >> 5;

    const int bid  = blockIdx.x;
    const int b    = bid & 1;
    const int h    = (bid >> 1) & 15;
    const int slot = bid >> 5;           // 0..15
    // round-robin co-residents {s, s+8} pair qt {15-s, s} -> 34 units/CU-pair;
    // linear dispatch is heavy-first.
    const int qt   = (slot < 8) ? 15 - slot : slot - 8;
    const int q0   = qt * 128;
    const int sq   = q0 + w * 32 + qc;

    // ---- Q fragments (B-operand): col=qc, k(d) = 16*ks + 8*h2 + j ----
    f16x8 qf[8];
    {
        const float* qrow = q + ((size_t)sq * NB + b) * (NH * DH) + h * DH;
        #pragma unroll
        for (int ks = 0; ks < 8; ++ks) {
            const int d0 = ks * 16 + h2 * 8;
            f32x4 a = *(const f32x4*)(qrow + d0);
            f32x4 c = *(const f32x4*)(qrow + d0 + 4);
            f16x8 t;
            t[0] = f2h(a.x * SCALE_L2E); t[1] = f2h(a.y * SCALE_L2E);
            t[2] = f2h(a.z * SCALE_L2E); t[3] = f2h(a.w * SCALE_L2E);
            t[4] = f2h(c.x * SCALE_L2E); t[5] = f2h(c.y * SCALE_L2E);
            t[6] = f2h(c.z * SCALE_L2E); t[7] = f2h(c.w * SCALE_L2E);
            qf[ks] = t;
        }
    }

    float m_run = sinks[h] * LOG2E;   // base-2 logit space
    float l_run = 1.0f;               // sink contribution
    f32x16 acc[4];                    // O^T: col=q (lane-local), rows=d
    #pragma unroll
    for (int i = 0; i < 4; ++i) acc[i] = (f32x16)(0.0f);

    const _Float16* ktiles = kws + (size_t)b * NKT * 8192;
    const _Float16* vtiles = vws + (size_t)b * NKT * 8192;
    const int ntiles = 2 * qt + 2;
    const int wlimit = q0 + w * 32 + 31;

    // prologue: stage K[0] into Kb[0]
    #pragma unroll
    for (int j = 0; j < 4; ++j) {
        const int off = (w * 4 + j) * 512;
        gload16(ktiles + off + lane * 8, &Kb[0][off]);
    }
    asm volatile("s_waitcnt vmcnt(0)" ::: "memory");
    __builtin_amdgcn_s_barrier();
    asm volatile("" ::: "memory");

    for (int it = 0; it < ntiles; ++it) {
        const int cur = it & 1;
        const bool haveK = (it + 1 < ntiles);

        // ---- issue V[it] -> Vb, then K[it+1] -> Kb[cur^1] ----
        {
            const _Float16* vt = vtiles + (size_t)it * 8192;
            #pragma unroll
            for (int j = 0; j < 4; ++j) {
                const int off = (w * 4 + j) * 512;
                gload16(vt + off + lane * 8, &Vb[off]);
            }
        }
        if (haveK) {
            const _Float16* kn = ktiles + (size_t)(it + 1) * 8192;
            #pragma unroll
            for (int j = 0; j < 4; ++j) {
                const int off = (w * 4 + j) * 512;
                gload16(kn + off + lane * 8, &Kb[cur ^ 1][off]);
            }
        }

        const int ktbase = it * 64;
        const bool alive = (ktbase <= wlimit);
        float sv[32];

        if (alive) {
            // ---- S^T = K * Q^T : col=q=qc, row=kv=(i&3)+8*(i>>2)+4*h2+32*mt ----
            f32x16 sa0 = (f32x16)(0.0f), sa1 = (f32x16)(0.0f);
            __builtin_amdgcn_s_setprio(1);
            #pragma unroll
            for (int ks = 0; ks < 8; ++ks) {
                const int col = ks * 16 + h2 * 8;
                const int e0 = (qc * 128 + col) ^ ((qc & 7) << 3);
                const int e1 = ((32 + qc) * 128 + col) ^ ((qc & 7) << 3);
                f16x8 k0 = *(const f16x8*)(&Kb[cur][e0]);
                f16x8 k1 = *(const f16x8*)(&Kb[cur][e1]);
                sa0 = __builtin_amdgcn_mfma_f32_32x32x16_f16(k0, qf[ks], sa0, 0, 0, 0);
                sa1 = __builtin_amdgcn_mfma_f32_32x32x16_f16(k1, qf[ks], sa1, 0, 0, 0);
            }
            __builtin_amdgcn_s_setprio(0);

            #pragma unroll
            for (int i = 0; i < 16; ++i) { sv[i] = sa0[i]; sv[16 + i] = sa1[i]; }

            // ---- causal mask (wave-uniform branch; near-diagonal tiles) ----
            if (ktbase + 63 > q0 + w * 32) {
                #pragma unroll
                for (int mt = 0; mt < 2; ++mt)
                    #pragma unroll
                    for (int i = 0; i < 16; ++i) {
                        const int tk = ktbase + (i & 3) + 8 * (i >> 2) + 4 * h2 + 32 * mt;
                        if (tk > sq) sv[mt * 16 + i] = -1e30f;
                    }
            }

            // ---- online softmax (base-2, lane-local stats for q=qc) ----
            float mx = sv[0];
            #pragma unroll
            for (int i = 1; i < 32; ++i) mx = fmaxf(mx, sv[i]);
            mx = fmaxf(mx, __shfl_xor(mx, 32));

            if (!__all(mx <= m_run + DEFER_THR)) {   // defer-max (T13)
                const float mnew = fmaxf(m_run, mx);
                const float corr = __builtin_amdgcn_exp2f(m_run - mnew);
                m_run = mnew;
                l_run *= corr;
                #pragma unroll
                for (int mt = 0; mt < 4; ++mt) acc[mt] *= corr;
            }

            float ls = 0.0f;
            #pragma unroll
            for (int i = 0; i < 32; ++i) {
                const float p = __builtin_amdgcn_exp2f(sv[i] - m_run);
                sv[i] = p;
                ls += p;
            }
            ls += __shfl_xor(ls, 32);
            l_run += ls;
        }

        // ---- V visibility: own V loads landed (K still in flight), then sync ----
        if (haveK) asm volatile("s_waitcnt vmcnt(4)" ::: "memory");
        else       asm volatile("s_waitcnt vmcnt(0)" ::: "memory");
        __builtin_amdgcn_s_barrier();
        asm volatile("" ::: "memory");

        if (alive) {
            // ---- P -> f16 A-frags in-register (cvt_pkrtz + permlane32_swap) ----
            unsigned int pw[4][4];
            #pragma unroll
            for (int mt = 0; mt < 2; ++mt) {
                unsigned int e0[4], e1[4];
                #pragma unroll
                for (int bq = 0; bq < 4; ++bq) {
                    e0[bq] = pkrtz(sv[mt * 16 + 4 * bq + 0], sv[mt * 16 + 4 * bq + 1]);
                    e1[bq] = pkrtz(sv[mt * 16 + 4 * bq + 2], sv[mt * 16 + 4 * bq + 3]);
                }
                #pragma unroll
                for (int kl = 0; kl < 2; ++kl) {
                    unsigned int a0 = e0[2 * kl], b0 = e0[2 * kl + 1];
                    unsigned int a1 = e1[2 * kl], b1 = e1[2 * kl + 1];
                    asm volatile("v_permlane32_swap_b32 %0, %1" : "+v"(a0), "+v"(b0));
                    asm volatile("v_permlane32_swap_b32 %0, %1" : "+v"(a1), "+v"(b1));
                    pw[mt * 2 + kl][0] = a0; pw[mt * 2 + kl][1] = a1;
                    pw[mt * 2 + kl][2] = b0; pw[mt * 2 + kl][3] = b1;
                }
            }

            // ---- O^T += V^T * P^T ----
            __builtin_amdgcn_s_setprio(1);
            #pragma unroll
            for (int ks = 0; ks < 4; ++ks) {
                u32x4 pu = { pw[ks][0], pw[ks][1], pw[ks][2], pw[ks][3] };
                f16x8 pf = __builtin_bit_cast(f16x8, pu);
                #pragma unroll
                for (int mt = 0; mt < 4; ++mt) {
                    const int d = mt * 32 + qc;
                    const int e = (d * 64 + ks * 16 + h2 * 8) ^ ((qc & 7) << 3);
                    f16x8 vf = *(const f16x8*)(&Vb[e]);
                    acc[mt] = __builtin_amdgcn_mfma_f32_32x32x16_f16(vf, pf, acc[mt], 0, 0, 0);
                }
            }
            __builtin_amdgcn_s_setprio(0);
        }

        // ---- end of iter: K[it+1] landed everywhere; Vb consumed ----
        asm volatile("s_waitcnt vmcnt(0)" ::: "memory");
        __builtin_amdgcn_s_barrier();
        asm volatile("" ::: "memory");
    }

    // ---- epilogue: lane-local normalize, f32x4 stores ----
    const float rl = 1.0f / l_run;
    float* orow = out + ((size_t)sq * NB + b) * (NH * DH) + h * DH;
    #pragma unroll
    for (int mt = 0; mt < 4; ++mt)
        #pragma unroll
        for (int rg = 0; rg < 4; ++rg) {
            f32x4 o = { acc[mt][4 * rg + 0] * rl, acc[mt][4 * rg + 1] * rl,
                        acc[mt][4 * rg + 2] * rl, acc[mt][4 * rg + 3] * rl };
            *(f32x4*)(orow + mt * 32 + rg * 8 + h2 * 4) = o;
        }
}

extern "C" void kernel_launch(void* const* d_in, const int* in_sizes, int n_in,
                              void* d_out, int out_size, void* d_ws, size_t ws_size,
                              hipStream_t stream) {
    const float* q     = (const float*)d_in[0];
    const float* k     = (const float*)d_in[1];
    const float* v     = (const float*)d_in[2];
    const float* sinks = (const float*)d_in[3];
    float* out = (float*)d_out;

    _Float16* kws = (_Float16*)d_ws;                        // 1 MB
    _Float16* vws = kws + (size_t)NB * NKT * 8192;          // 1 MB

    prepack<<<dim3(128), 256, 0, stream>>>(k, v, kws, vws);
    attn_fwd<<<dim3(NQT * NB * NH), 256, 0, stream>>>(q, kws, vws, sinks, out);
}

// Round 15
// 72.842 us; speedup vs baseline: 1.9587x; 1.8046x over previous
//
#include <hip/hip_runtime.h>

#define SQ 2048
#define NB 2
#define NH 16
#define DH 128
#define NKT 32                       // 64-row KV tiles
#define NQT 32                       // 64-row Q tiles
#define SCALE_L2E 0.1275174609f      // (1/sqrt(128)) * log2(e)
#define LOG2E 1.4426950408889634f
#define DEFER_THR 11.0f              // ~8 nats in log2 units

typedef _Float16 f16x8 __attribute__((ext_vector_type(8)));
typedef _Float16 f16x4 __attribute__((ext_vector_type(4)));
typedef float f32x4 __attribute__((ext_vector_type(4)));

static __device__ __forceinline__ _Float16 f2h(float f) { return (_Float16)f; }

// ---------------------------------------------------------------------------
// Pre-pass: K -> fp16 [b][t][64][128] XOR-swizzled,
//           V -> fp16 [b][t][128][64] transposed, XOR-swizzled.
// ---------------------------------------------------------------------------
__global__ __launch_bounds__(256)
void prepack(const float* __restrict__ k, const float* __restrict__ v,
             _Float16* __restrict__ kws, _Float16* __restrict__ vws) {
    const int bid   = blockIdx.x;        // 0..127
    const int which = bid >> 6;          // 0 = K, 1 = V
    const int b     = (bid >> 5) & 1;
    const int t     = bid & 31;
    const int tid   = threadIdx.x;

    if (which == 0) {
        const float* kbase = k + (size_t)t * 64 * (NB * DH) + b * DH;
        _Float16* dst = kws + ((size_t)b * NKT + t) * 8192;
        #pragma unroll
        for (int p = 0; p < 8; ++p) {
            const int id4 = p * 256 + tid;
            const int row = id4 >> 5;
            const int c0  = (id4 & 31) << 2;
            f32x4 a = *(const f32x4*)(kbase + (size_t)row * (NB * DH) + c0);
            const int e = (row * 128 + c0) ^ ((row & 7) << 3);
            f16x4 pk = { f2h(a.x), f2h(a.y), f2h(a.z), f2h(a.w) };
            *(f16x4*)(dst + e) = pk;
        }
    } else {
        const float* vbase = v + b * DH;
        _Float16* dst = vws + ((size_t)b * NKT + t) * 8192;
        const int d    = tid & 127;
        const int half = tid >> 7;
        #pragma unroll
        for (int p = 0; p < 8; ++p) {
            const int c0 = (p * 2 + half) * 4;
            float a0 = vbase[(size_t)(t * 64 + c0 + 0) * (NB * DH) + d];
            float a1 = vbase[(size_t)(t * 64 + c0 + 1) * (NB * DH) + d];
            float a2 = vbase[(size_t)(t * 64 + c0 + 2) * (NB * DH) + d];
            float a3 = vbase[(size_t)(t * 64 + c0 + 3) * (NB * DH) + d];
            const int e = (d * 64 + c0) ^ ((d & 7) << 3);
            f16x4 pk = { f2h(a0), f2h(a1), f2h(a2), f2h(a3) };
            *(f16x4*)(dst + e) = pk;
        }
    }
}

static __device__ __forceinline__ void gload16(const _Float16* gsrc, _Float16* ldst) {
    __builtin_amdgcn_global_load_lds(
        (const __attribute__((address_space(1))) void*)gsrc,
        (__attribute__((address_space(3))) void*)ldst, 16, 0, 0);
}

// ---------------------------------------------------------------------------
// Softmax + P-write + PV for one context (R7-verified layouts).
// ---------------------------------------------------------------------------
static __device__ __forceinline__ void softmax_pv(
    const _Float16* __restrict__ Vc, _Float16* __restrict__ Pw,
    float* __restrict__ sv, f32x4* __restrict__ acc,
    float& m_run, float& l_run, int r, int g, int lane) {

    float m0 = fmaxf(fmaxf(sv[0], sv[1]), fmaxf(sv[2], sv[3]));
    float m1 = fmaxf(fmaxf(sv[4], sv[5]), fmaxf(sv[6], sv[7]));
    float m2 = fmaxf(fmaxf(sv[8], sv[9]), fmaxf(sv[10], sv[11]));
    float m3 = fmaxf(fmaxf(sv[12], sv[13]), fmaxf(sv[14], sv[15]));
    float mx = fmaxf(fmaxf(m0, m1), fmaxf(m2, m3));
    mx = fmaxf(mx, __shfl_xor(mx, 16));
    mx = fmaxf(mx, __shfl_xor(mx, 32));

    if (!__all(mx <= m_run + DEFER_THR)) {       // defer-max (T13)
        const float mnew = fmaxf(m_run, mx);
        const float corr = __builtin_amdgcn_exp2f(m_run - mnew);
        m_run = mnew;
        l_run *= corr;
        #pragma unroll
        for (int i = 0; i < 4; ++i) {
            const float ci = __shfl(corr, (lane & 48) | (g * 4 + i));
            #pragma unroll
            for (int nb = 0; nb < 8; ++nb) acc[nb][i] *= ci;
        }
    }

    #pragma unroll
    for (int i = 0; i < 16; ++i)
        sv[i] = __builtin_amdgcn_exp2f(sv[i] - m_run);
    float t0 = (sv[0] + sv[1]) + (sv[2] + sv[3]);
    float t1 = (sv[4] + sv[5]) + (sv[6] + sv[7]);
    float t2 = (sv[8] + sv[9]) + (sv[10] + sv[11]);
    float t3 = (sv[12] + sv[13]) + (sv[14] + sv[15]);
    float ls = (t0 + t1) + (t2 + t3);
    ls += __shfl_xor(ls, 16);
    ls += __shfl_xor(ls, 32);
    l_run += ls;

    #pragma unroll
    for (int ct = 0; ct < 4; ++ct) {
        f16x4 pb = { f2h(sv[ct * 4 + 0]), f2h(sv[ct * 4 + 1]),
                     f2h(sv[ct * 4 + 2]), f2h(sv[ct * 4 + 3]) };
        const int c0 = ct * 16 + g * 4;
        const int e = (r * 64 + c0) ^ ((r & 7) << 3);
        *(f16x4*)(&Pw[e]) = pb;
    }

    #pragma unroll
    for (int cc = 0; cc < 2; ++cc) {
        const int ep = (r * 64 + cc * 32 + g * 8) ^ ((r & 7) << 3);
        f16x8 pf = *(const f16x8*)(&Pw[ep]);
        __builtin_amdgcn_s_setprio(1);
        #pragma unroll
        for (int nb = 0; nb < 8; ++nb) {
            const int d = nb * 16 + r;
            const int ev = (d * 64 + cc * 32 + g * 8) ^ ((d & 7) << 3);
            f16x8 vf = *(const f16x8*)(&Vc[ev]);
            acc[nb] = __builtin_amdgcn_mfma_f32_16x16x32_f16(pf, vf, acc[nb], 0, 0, 0);
        }
        __builtin_amdgcn_s_setprio(0);
    }
}

// ---------------------------------------------------------------------------
// Hot kernel: causal-folded {j, 31-j}, 33 updates/block, FUSED K/V fragment
// reads when both contexts alive (kf/vf read once, used by both contexts).
// ---------------------------------------------------------------------------
__global__ __launch_bounds__(256, 2)
void attn_fwd(const float* __restrict__ q, const _Float16* __restrict__ kws,
              const _Float16* __restrict__ vws, const float* __restrict__ sinks,
              float* __restrict__ out) {
    __shared__ _Float16 Kb[2][8192];     // 64x128 swizzled, dbuf (32 KB)
    __shared__ _Float16 Vb[2][8192];     // 128x64 (V^T) swizzled, dbuf (32 KB)
    __shared__ _Float16 Plds[4][2][1024];// per-wave, per-context 16x64 (16 KB)

    const int tid  = threadIdx.x;
    const int w    = tid >> 6;
    const int lane = tid & 63;
    const int r    = lane & 15;
    const int g    = lane >> 4;

    const int bid = blockIdx.x;
    const int bh  = bid & 31;
    const int b   = bh & 1;
    const int h   = bh >> 1;
    const int j   = bid >> 5;            // 0..15
    const int qtL = j, qtH = NQT - 1 - j;
    const int q0L = qtL * 64, q0H = qtH * 64;
    const int sqL = q0L + w * 16 + r, sqH = q0H + w * 16 + r;

    // ---- Q fragments for both contexts, SCALE*log2e folded ----
    f16x8 qfL[4], qfH[4];
    #pragma unroll
    for (int ctx = 0; ctx < 2; ++ctx) {
        const int sq = ctx ? sqH : sqL;
        f16x8* qf = ctx ? qfH : qfL;
        const float* qrow = q + ((size_t)sq * NB + b) * (NH * DH) + h * DH;
        #pragma unroll
        for (int kc = 0; kc < 4; ++kc) {
            const int d0 = kc * 32 + g * 8;
            f32x4 a = *(const f32x4*)(qrow + d0);
            f32x4 c = *(const f32x4*)(qrow + d0 + 4);
            f16x8 t;
            t[0] = f2h(a.x * SCALE_L2E); t[1] = f2h(a.y * SCALE_L2E);
            t[2] = f2h(a.z * SCALE_L2E); t[3] = f2h(a.w * SCALE_L2E);
            t[4] = f2h(c.x * SCALE_L2E); t[5] = f2h(c.y * SCALE_L2E);
            t[6] = f2h(c.z * SCALE_L2E); t[7] = f2h(c.w * SCALE_L2E);
            qf[kc] = t;
        }
    }

    const float sink2 = sinks[h] * LOG2E;
    float mL = sink2, lL = 1.0f, mH = sink2, lH = 1.0f;
    f32x4 accL[8], accH[8];
    #pragma unroll
    for (int i = 0; i < 8; ++i) { accL[i] = (f32x4)(0.0f); accH[i] = (f32x4)(0.0f); }

    const _Float16* ktiles = kws + (size_t)b * NKT * 8192;
    const _Float16* vtiles = vws + (size_t)b * NKT * 8192;
    const int ntiles = qtH + 1;          // 17..32

    // prologue: stage tile 0
    #pragma unroll
    for (int p = 0; p < 4; ++p) {
        const int off = (p * 256 + tid) * 8;
        gload16(ktiles + off, &Kb[0][off]);
        gload16(vtiles + off, &Vb[0][off]);
    }
    asm volatile("s_waitcnt vmcnt(0)" ::: "memory");
    __builtin_amdgcn_s_barrier();
    asm volatile("" ::: "memory");

    for (int it = 0; it < ntiles; ++it) {
        const int cur = it & 1;
        if (it + 1 < ntiles) {
            const _Float16* kn = ktiles + (size_t)(it + 1) * 8192;
            const _Float16* vn = vtiles + (size_t)(it + 1) * 8192;
            #pragma unroll
            for (int p = 0; p < 4; ++p) {
                const int off = (p * 256 + tid) * 8;
                gload16(kn + off, &Kb[cur ^ 1][off]);
                gload16(vn + off, &Vb[cur ^ 1][off]);
            }
        }

        const int ktb = it * 64;
        const bool aliveL = (ktb <= q0L + w * 16 + 15);

        if (aliveL) {
            // ======== FUSED path: kf read ONCE for both contexts ========
            float svL[16], svH[16];
            __builtin_amdgcn_s_setprio(1);
            #pragma unroll
            for (int ct = 0; ct < 4; ++ct) {
                f32x4 saL = (f32x4)(0.0f), saH = (f32x4)(0.0f);
                const int c = ct * 16 + r;
                #pragma unroll
                for (int kc = 0; kc < 4; ++kc) {
                    const int e = (c * 128 + kc * 32 + g * 8) ^ ((c & 7) << 3);
                    f16x8 kf = *(const f16x8*)(&Kb[cur][e]);
                    saL = __builtin_amdgcn_mfma_f32_16x16x32_f16(kf, qfL[kc], saL, 0, 0, 0);
                    saH = __builtin_amdgcn_mfma_f32_16x16x32_f16(kf, qfH[kc], saH, 0, 0, 0);
                }
                #pragma unroll
                for (int i = 0; i < 4; ++i) { svL[ct * 4 + i] = saL[i]; svH[ct * 4 + i] = saH[i]; }
            }
            __builtin_amdgcn_s_setprio(0);

            // causal mask, each context with its own guard
            if (ktb + 63 > q0L + w * 16) {
                #pragma unroll
                for (int ct = 0; ct < 4; ++ct)
                    #pragma unroll
                    for (int i = 0; i < 4; ++i) {
                        const int tk = ktb + ct * 16 + g * 4 + i;
                        if (tk > sqL) svL[ct * 4 + i] = -1e30f;
                    }
            }
            if (ktb + 63 > q0H + w * 16) {
                #pragma unroll
                for (int ct = 0; ct < 4; ++ct)
                    #pragma unroll
                    for (int i = 0; i < 4; ++i) {
                        const int tk = ktb + ct * 16 + g * 4 + i;
                        if (tk > sqH) svH[ct * 4 + i] = -1e30f;
                    }
            }

            // softmax both contexts (VALU), P both -> LDS
            softmax_pv_prep:;
            // -- inline softmax for L and H, then fused PV over shared vf --
            {
                // L softmax + P write
                float m0 = fmaxf(fmaxf(svL[0], svL[1]), fmaxf(svL[2], svL[3]));
                float m1 = fmaxf(fmaxf(svL[4], svL[5]), fmaxf(svL[6], svL[7]));
                float m2 = fmaxf(fmaxf(svL[8], svL[9]), fmaxf(svL[10], svL[11]));
                float m3 = fmaxf(fmaxf(svL[12], svL[13]), fmaxf(svL[14], svL[15]));
                float mx = fmaxf(fmaxf(m0, m1), fmaxf(m2, m3));
                mx = fmaxf(mx, __shfl_xor(mx, 16));
                mx = fmaxf(mx, __shfl_xor(mx, 32));
                if (!__all(mx <= mL + DEFER_THR)) {
                    const float mnew = fmaxf(mL, mx);
                    const float corr = __builtin_amdgcn_exp2f(mL - mnew);
                    mL = mnew; lL *= corr;
                    #pragma unroll
                    for (int i = 0; i < 4; ++i) {
                        const float ci = __shfl(corr, (lane & 48) | (g * 4 + i));
                        #pragma unroll
                        for (int nb = 0; nb < 8; ++nb) accL[nb][i] *= ci;
                    }
                }
                #pragma unroll
                for (int i = 0; i < 16; ++i) svL[i] = __builtin_amdgcn_exp2f(svL[i] - mL);
                float t0 = (svL[0] + svL[1]) + (svL[2] + svL[3]);
                float t1 = (svL[4] + svL[5]) + (svL[6] + svL[7]);
                float t2 = (svL[8] + svL[9]) + (svL[10] + svL[11]);
                float t3 = (svL[12] + svL[13]) + (svL[14] + svL[15]);
                float ls = (t0 + t1) + (t2 + t3);
                ls += __shfl_xor(ls, 16);
                ls += __shfl_xor(ls, 32);
                lL += ls;
                #pragma unroll
                for (int ct = 0; ct < 4; ++ct) {
                    f16x4 pb = { f2h(svL[ct * 4 + 0]), f2h(svL[ct * 4 + 1]),
                                 f2h(svL[ct * 4 + 2]), f2h(svL[ct * 4 + 3]) };
                    const int e = (r * 64 + ct * 16 + g * 4) ^ ((r & 7) << 3);
                    *(f16x4*)(&Plds[w][0][e]) = pb;
                }
            }
            {
                // H softmax + P write
                float m0 = fmaxf(fmaxf(svH[0], svH[1]), fmaxf(svH[2], svH[3]));
                float m1 = fmaxf(fmaxf(svH[4], svH[5]), fmaxf(svH[6], svH[7]));
                float m2 = fmaxf(fmaxf(svH[8], svH[9]), fmaxf(svH[10], svH[11]));
                float m3 = fmaxf(fmaxf(svH[12], svH[13]), fmaxf(svH[14], svH[15]));
                float mx = fmaxf(fmaxf(m0, m1), fmaxf(m2, m3));
                mx = fmaxf(mx, __shfl_xor(mx, 16));
                mx = fmaxf(mx, __shfl_xor(mx, 32));
                if (!__all(mx <= mH + DEFER_THR)) {
                    const float mnew = fmaxf(mH, mx);
                    const float corr = __builtin_amdgcn_exp2f(mH - mnew);
                    mH = mnew; lH *= corr;
                    #pragma unroll
                    for (int i = 0; i < 4; ++i) {
                        const float ci = __shfl(corr, (lane & 48) | (g * 4 + i));
                        #pragma unroll
                        for (int nb = 0; nb < 8; ++nb) accH[nb][i] *= ci;
                    }
                }
                #pragma unroll
                for (int i = 0; i < 16; ++i) svH[i] = __builtin_amdgcn_exp2f(svH[i] - mH);
                float t0 = (svH[0] + svH[1]) + (svH[2] + svH[3]);
                float t1 = (svH[4] + svH[5]) + (svH[6] + svH[7]);
                float t2 = (svH[8] + svH[9]) + (svH[10] + svH[11]);
                float t3 = (svH[12] + svH[13]) + (svH[14] + svH[15]);
                float ls = (t0 + t1) + (t2 + t3);
                ls += __shfl_xor(ls, 16);
                ls += __shfl_xor(ls, 32);
                lH += ls;
                #pragma unroll
                for (int ct = 0; ct < 4; ++ct) {
                    f16x4 pb = { f2h(svH[ct * 4 + 0]), f2h(svH[ct * 4 + 1]),
                                 f2h(svH[ct * 4 + 2]), f2h(svH[ct * 4 + 3]) };
                    const int e = (r * 64 + ct * 16 + g * 4) ^ ((r & 7) << 3);
                    *(f16x4*)(&Plds[w][1][e]) = pb;
                }
            }

            // fused PV: vf read ONCE for both contexts
            #pragma unroll
            for (int cc = 0; cc < 2; ++cc) {
                const int ep = (r * 64 + cc * 32 + g * 8) ^ ((r & 7) << 3);
                f16x8 pfL = *(const f16x8*)(&Plds[w][0][ep]);
                f16x8 pfH = *(const f16x8*)(&Plds[w][1][ep]);
                __builtin_amdgcn_s_setprio(1);
                #pragma unroll
                for (int nb = 0; nb < 8; ++nb) {
                    const int d = nb * 16 + r;
                    const int ev = (d * 64 + cc * 32 + g * 8) ^ ((d & 7) << 3);
                    f16x8 vf = *(const f16x8*)(&Vb[cur][ev]);
                    accL[nb] = __builtin_amdgcn_mfma_f32_16x16x32_f16(pfL, vf, accL[nb], 0, 0, 0);
                    accH[nb] = __builtin_amdgcn_mfma_f32_16x16x32_f16(pfH, vf, accH[nb], 0, 0, 0);
                }
                __builtin_amdgcn_s_setprio(0);
            }
        } else {
            // ======== single-context path (H only), R7-identical ========
            float svH[16];
            __builtin_amdgcn_s_setprio(1);
            #pragma unroll
            for (int ct = 0; ct < 4; ++ct) {
                f32x4 sa = (f32x4)(0.0f);
                const int c = ct * 16 + r;
                #pragma unroll
                for (int kc = 0; kc < 4; ++kc) {
                    const int e = (c * 128 + kc * 32 + g * 8) ^ ((c & 7) << 3);
                    f16x8 kf = *(const f16x8*)(&Kb[cur][e]);
                    sa = __builtin_amdgcn_mfma_f32_16x16x32_f16(kf, qfH[kc], sa, 0, 0, 0);
                }
                #pragma unroll
                for (int i = 0; i < 4; ++i) svH[ct * 4 + i] = sa[i];
            }
            __builtin_amdgcn_s_setprio(0);

            if (ktb + 63 > q0H + w * 16) {
                #pragma unroll
                for (int ct = 0; ct < 4; ++ct)
                    #pragma unroll
                    for (int i = 0; i < 4; ++i) {
                        const int tk = ktb + ct * 16 + g * 4 + i;
                        if (tk > sqH) svH[ct * 4 + i] = -1e30f;
                    }
            }

            softmax_pv(Vb[cur], Plds[w][1], svH, accH, mH, lH, r, g, lane);
        }

        asm volatile("s_waitcnt vmcnt(0)" ::: "memory");
        __builtin_amdgcn_s_barrier();
        asm volatile("" ::: "memory");
    }

    // ---- epilogue: normalize + store both contexts ----
    #pragma unroll
    for (int ctx = 0; ctx < 2; ++ctx) {
        const int q0 = ctx ? q0H : q0L;
        const float lr = ctx ? lH : lL;
        const f32x4* acc = ctx ? accH : accL;
        #pragma unroll
        for (int i = 0; i < 4; ++i) {
            const float li = __shfl(lr, (lane & 48) | (g * 4 + i));
            const float rl = 1.0f / li;
            const int row = q0 + w * 16 + g * 4 + i;
            float* op = out + ((size_t)row * NB + b) * (NH * DH) + h * DH + r;
            #pragma unroll
            for (int nb = 0; nb < 8; ++nb)
                op[nb * 16] = acc[nb][i] * rl;
        }
    }
}

extern "C" void kernel_launch(void* const* d_in, const int* in_sizes, int n_in,
                              void* d_out, int out_size, void* d_ws, size_t ws_size,
                              hipStream_t stream) {
    const float* q     = (const float*)d_in[0];
    const float* k     = (const float*)d_in[1];
    const float* v     = (const float*)d_in[2];
    const float* sinks = (const float*)d_in[3];
    float* out = (float*)d_out;

    _Float16* kws = (_Float16*)d_ws;                        // 1 MB
    _Float16* vws = kws + (size_t)NB * NKT * 8192;          // 1 MB

    prepack<<<dim3(128), 256, 0, stream>>>(k, v, kws, vws);
    attn_fwd<<<dim3((NQT / 2) * NB * NH), 256, 0, stream>>>(q, kws, vws, sinks, out);
}